// Round 16
// baseline (183.083 us; speedup 1.0000x reference)
//
#include <hip/hip_runtime.h>

#define BB 64
#define SS 1024
#define HH 512
#define EE 512
#define VV 32000
#define PP 40

typedef __attribute__((ext_vector_type(8))) __bf16 bf16x8;
typedef __attribute__((ext_vector_type(4))) float f32x4;
typedef __attribute__((ext_vector_type(8))) unsigned short us8_t;
typedef __attribute__((ext_vector_type(4))) unsigned short us4_t;

__device__ inline float fast_tanh(float x) {
    float e = __expf(-2.0f * fabsf(x));
    float t = (1.0f - e) / (1.0f + e);
    return copysignf(t, x);
}
__device__ inline float sigmf(float x) { return 1.0f / (1.0f + __expf(-x)); }

// non-volatile: pure register computation, schedulable/CSE-able (R12 lesson)
__device__ inline unsigned int cvtpk(float lo, float hi) {
    unsigned int r;
    asm("v_cvt_pk_bf16_f32 %0, %1, %2" : "=v"(r) : "v"(lo), "v"(hi));
    return r;
}
__device__ inline us8_t pack8c(float4 x, float4 y) {
    union { unsigned int u[4]; us8_t v; } r;
    r.u[0] = cvtpk(x.x, x.y); r.u[1] = cvtpk(x.z, x.w);
    r.u[2] = cvtpk(y.x, y.y); r.u[3] = cvtpk(y.z, y.w);
    return r.v;
}

typedef __attribute__((address_space(1))) const unsigned char gas_t;
typedef __attribute__((address_space(3))) unsigned char las_t;
__device__ inline void gload16(const void* g, void* l) {
    __builtin_amdgcn_global_load_lds((gas_t*)g, (las_t*)l, 16, 0, 0);
}

// ---------------------------------------------------------------------------
// k_pre: 0..63 qs = hidden @ W_s^T  PLUS emb16/h16v build (k_build fused);
// 64..95 W_h->bf16; 96..351 gate; 352..359 ctx zero.
// ---------------------------------------------------------------------------
__global__ __launch_bounds__(256)
void k_pre(const float* __restrict__ hidden, const float* __restrict__ Ws,
           const float* __restrict__ Wh, const float* __restrict__ pos,
           const float* __restrict__ Wp, const float* __restrict__ bp,
           const int* __restrict__ tok, const float* __restrict__ embt,
           unsigned short* __restrict__ wh16, float* __restrict__ qs,
           float* __restrict__ gate, float* __restrict__ ctx,
           unsigned short* __restrict__ emb16, unsigned short* __restrict__ h16v) {
    int blk = blockIdx.x, t = threadIdx.x;
    if (blk < 64) {
        __shared__ float hb[HH];
        int b = blk;
        for (int i = t; i < HH; i += 256) hb[i] = hidden[b * HH + i];
        __syncthreads();
        for (int n = t; n < HH; n += 256) {
            const float* wr = Ws + (size_t)n * HH;
            float acc = 0.0f;
#pragma unroll 4
            for (int k = 0; k < HH; k += 4) {
                float4 w = *(const float4*)(wr + k);
                acc += w.x * hb[k] + w.y * hb[k + 1] + w.z * hb[k + 2] + w.w * hb[k + 3];
            }
            qs[b * HH + n] = acc;
        }
        // fused k_build part: emb16 + h16v for batch b
        const float* er = embt + (size_t)tok[b] * EE;
        for (int i = 2 * t; i < HH; i += 512) {
            *(unsigned int*)(emb16 + b * 512 + i) = cvtpk(er[i], er[i + 1]);
            *(unsigned int*)(h16v + b * 512 + i) = cvtpk(hb[i], hb[i + 1]);
        }
    } else if (blk < 96) {
        int base = (blk - 64) * 8192 + t * 4;
#pragma unroll
        for (int j = 0; j < 8; ++j) {
            int idx = base + j * 1024;
            float4 x = *(const float4*)(Wh + idx);
            union { unsigned int u[2]; us4_t v; } r;
            r.u[0] = cvtpk(x.x, x.y); r.u[1] = cvtpk(x.z, x.w);
            *(us4_t*)(wh16 + idx) = r.v;
        }
    } else if (blk < 352) {
        int idx = (blk - 96) * 256 + t;  // 0..65535 = b*S+s
        const float* pr = pos + (size_t)idx * PP;
        float acc = bp[0];
#pragma unroll
        for (int j = 0; j < 10; ++j) {
            float4 x = *(const float4*)(pr + j * 4);
            acc += x.x * Wp[j * 4] + x.y * Wp[j * 4 + 1] + x.z * Wp[j * 4 + 2] + x.w * Wp[j * 4 + 3];
        }
        gate[idx] = sigmf(acc);
    } else {
        int idx = (blk - 352) * 256 + t;  // ctx zero
#pragma unroll
        for (int j = 0; j < 16; ++j) ctx[idx * 16 + j] = 0.0f;
    }
}

// ---------------------------------------------------------------------------
// k_scores v11: C(s,n) = enc @ wh16^T, both operands bf16 in LDS.
// A: reg-staged (f32 load -> cvtpk -> swizzled ds_write_b128, T14 split);
// B: gload_lds with pre-swizzled source. Tile 128s x 256n, BK=32, 16 tiles,
// 8 waves (2m x 4n). Counted vmcnt keeps A(kt+2) f32 loads + B(kt+1)
// gload_lds in flight across the single barrier per tile.
// Swizzle (both operands, bf16 64B rows): key = ((row>>1)&3)<<4, applied on
// A ds_write + both reads; B source pre-swizzled (rule #21). 2-way max.
// grid 1024 = nh(2) x b(64) x sc(8) (nh-siblings same XCD -> L3 dedups enc).
// ---------------------------------------------------------------------------
__global__ __launch_bounds__(512)
void k_scores(const float* __restrict__ enc,
              const unsigned short* __restrict__ wh16,
              const float* __restrict__ qs, const float* __restrict__ Vw,
              float* __restrict__ part) {
    __shared__ unsigned short Abuf[2][4096];   // 2 x 8KB  [128 r][32 k] bf16 swz
    __shared__ unsigned short Bbuf[2][8192];   // 2 x 16KB [256 r][32 k] bf16 swz
    __shared__ float pbuf[4][128];
    int bid = blockIdx.x;
    int nh = bid >> 9, rest = bid & 511;
    int b = rest >> 3, sc = rest & 7;
    int s0 = sc * 128, n0 = nh * 256;
    int tid = threadIdx.x;
    int w = tid >> 6, lane = tid & 63;
    int wm = w >> 2, wn = w & 3;
    int l15 = lane & 15, lq = lane >> 4;

    float qv[4], vw[4];
#pragma unroll
    for (int nf = 0; nf < 4; ++nf) {
        int n = n0 + wn * 64 + nf * 16 + l15;
        qv[nf] = qs[b * HH + n];
        vw[nf] = Vw[n];
    }

    // A staging: thread -> row = tid>>2 (128 rows), seg = tid&3 (8 floats each)
    int arow = tid >> 2, aseg = tid & 3;
    int akeyw = (arow >> 1) & 3;
    const float* aSrc = enc + (size_t)(b * SS + s0 + arow) * HH + aseg * 8;
    int aWr = arow * 64 + ((aseg ^ akeyw) << 4);   // byte offset in Abuf

    // B staging via gload_lds: row = p*128 + w*16 + (lane>>2); linear LDS dest
    unsigned int colbB = (unsigned int)((((lane & 3) ^ ((lane >> 3) & 3)) & 3) << 4);
    const char* gB0 = (const char*)(wh16 + (size_t)n0 * HH);
    int bRowS = w * 16 + (lane >> 2);    // + p*128
    int ldsOffB = w * 1024 + lane * 16;  // + p*8192 (bytes)

    // frag read bases (byte) + swizzle keys
    int aRdB[4], akey[4], bRdB[4], bkey[4];
#pragma unroll
    for (int mf = 0; mf < 4; ++mf) {
        int r = wm * 64 + mf * 16 + l15;
        aRdB[mf] = r * 64;
        akey[mf] = ((r >> 1) & 3) << 4;
    }
#pragma unroll
    for (int nf = 0; nf < 4; ++nf) {
        int r = wn * 64 + nf * 16 + l15;
        bRdB[nf] = r * 64;
        bkey[nf] = ((r >> 1) & 3) << 4;
    }

    f32x4 acc[4][4];
#pragma unroll
    for (int mf = 0; mf < 4; ++mf)
#pragma unroll
        for (int nf = 0; nf < 4; ++nf) acc[mf][nf] = (f32x4){0.f, 0.f, 0.f, 0.f};

#define COMPUTE(BUF)                                                            \
    {                                                                           \
        us8_t af[4], bfr[4];                                                    \
        _Pragma("unroll")                                                       \
        for (int mf = 0; mf < 4; ++mf)                                          \
            af[mf] = *(const us8_t*)((const char*)Abuf[BUF] + aRdB[mf] +        \
                                     ((lq << 4) ^ akey[mf]));                   \
        _Pragma("unroll")                                                       \
        for (int nf = 0; nf < 4; ++nf)                                          \
            bfr[nf] = *(const us8_t*)((const char*)Bbuf[BUF] + bRdB[nf] +       \
                                      ((lq << 4) ^ bkey[nf]));                  \
        _Pragma("unroll")                                                       \
        for (int mf = 0; mf < 4; ++mf)                                          \
            _Pragma("unroll")                                                   \
            for (int nf = 0; nf < 4; ++nf)                                      \
                acc[mf][nf] = __builtin_amdgcn_mfma_f32_16x16x32_bf16(          \
                    __builtin_bit_cast(bf16x8, af[mf]),                         \
                    __builtin_bit_cast(bf16x8, bfr[nf]), acc[mf][nf], 0, 0, 0); \
    }

    // prologue: A(0) loads, B(0) gloads, write A(0), issue A(1)
    float4 xa0 = *(const float4*)(aSrc);
    float4 xa1 = *(const float4*)(aSrc + 4);
#pragma unroll
    for (int p = 0; p < 2; ++p)
        gload16(gB0 + (size_t)(p * 128 + bRowS) * 1024 + colbB,
                (char*)Bbuf[0] + p * 8192 + ldsOffB);
    asm volatile("s_waitcnt vmcnt(2)" ::: "memory");     // A(0) data ready
    *(us8_t*)((char*)Abuf[0] + aWr) = pack8c(xa0, xa1);
    xa0 = *(const float4*)(aSrc + 32);                   // issue A(1)
    xa1 = *(const float4*)(aSrc + 36);
    asm volatile("s_waitcnt vmcnt(2)" ::: "memory");     // B(0) in LDS, A(1) flying
    asm volatile("s_waitcnt lgkmcnt(0)" ::: "memory");
    __builtin_amdgcn_s_barrier();

#pragma unroll
    for (int kt = 0; kt < 16; ++kt) {
        if (kt < 15) {
            // issue B(kt+1) gloads -> other buffer
#pragma unroll
            for (int p = 0; p < 2; ++p)
                gload16(gB0 + (size_t)(p * 128 + bRowS) * 1024 + (kt + 1) * 64 + colbB,
                        (char*)Bbuf[(kt + 1) & 1] + p * 8192 + ldsOffB);
            // A(kt+1) regs ready (oldest 2 of 4 outstanding)
            asm volatile("s_waitcnt vmcnt(2)" ::: "memory");
            *(us8_t*)((char*)Abuf[(kt + 1) & 1] + aWr) = pack8c(xa0, xa1);
            if (kt < 14) {                               // issue A(kt+2)
                const float* g = aSrc + (kt + 2) * 32;
                xa0 = *(const float4*)(g);
                xa1 = *(const float4*)(g + 4);
            }
        }
        COMPUTE(kt & 1);
        if (kt < 14) {
            asm volatile("s_waitcnt vmcnt(2)" ::: "memory");   // B(kt+1) landed
        } else if (kt == 14) {
            asm volatile("s_waitcnt vmcnt(0)" ::: "memory");
        }
        if (kt < 15) {
            asm volatile("s_waitcnt lgkmcnt(0)" ::: "memory");
            __builtin_amdgcn_s_barrier();
        }
    }
#undef COMPUTE

    // epilogue: p(s) = sum_n Vw[n]*tanh(C + qs[n]); reduce over nf + l15 lanes
#pragma unroll
    for (int mf = 0; mf < 4; ++mf)
#pragma unroll
        for (int r = 0; r < 4; ++r) {
            float p = 0.0f;
#pragma unroll
            for (int nf = 0; nf < 4; ++nf)
                p += vw[nf] * fast_tanh(acc[mf][nf][r] + qv[nf]);
            p += __shfl_xor(p, 1, 64);
            p += __shfl_xor(p, 2, 64);
            p += __shfl_xor(p, 4, 64);
            p += __shfl_xor(p, 8, 64);
            if (l15 == 0) pbuf[wn][wm * 64 + mf * 16 + lq * 4 + r] = p;
        }
    __syncthreads();
    if (tid < 128) {
        part[nh * (BB * SS) + b * SS + s0 + tid] =
            pbuf[0][tid] + pbuf[1][tid] + pbuf[2][tid] + pbuf[3][tid];
    }
}

// ---------------------------------------------------------------------------
// k_context (softmax fused, f32 enc): combines 2 n-half partials, redundant
// row denominator, attn write, context accumulation.
// ---------------------------------------------------------------------------
__global__ __launch_bounds__(256)
void k_context(const float* __restrict__ enc, const float* __restrict__ part,
               const float* __restrict__ gate, const unsigned char* __restrict__ mask,
               float* __restrict__ attn, float* __restrict__ ctx) {
    int b = blockIdx.x >> 4, chunk = blockIdx.x & 15;
    int s0 = chunk * 64, t = threadIdx.x;
    int w = t >> 6, ln = t & 63;
    float sum = 0.0f;
#pragma unroll
    for (int j = 0; j < 4; ++j) {
        int s = j * 256 + t;
        float raw = part[b * SS + s] + part[BB * SS + b * SS + s];
        float v = mask[b * SS + s] ? -1e30f : raw * gate[b * SS + s];
        sum += __expf(v);
    }
#pragma unroll
    for (int off = 1; off < 64; off <<= 1) sum += __shfl_xor(sum, off, 64);
    __shared__ float sl[4];
    if (ln == 0) sl[w] = sum;
    __syncthreads();
    float inv = 1.0f / (sl[0] + sl[1] + sl[2] + sl[3]);

    __shared__ float aw[64];
    if (t < 64) {
        int s = s0 + t;
        float raw = part[b * SS + s] + part[BB * SS + b * SS + s];
        float v = mask[b * SS + s] ? -1e30f : raw * gate[b * SS + s];
        float a = __expf(v) * inv;
        aw[t] = a;
        attn[b * SS + s] = a;
    }
    __syncthreads();

    const float* eb = enc + ((size_t)(b * SS + s0)) * HH + 2 * t;
    float a0 = 0.f, a1 = 0.f;
#pragma unroll 4
    for (int s = 0; s < 64; ++s) {
        float2 u = *(const float2*)(eb + (size_t)s * HH);
        a0 += aw[s] * u.x;
        a1 += aw[s] * u.y;
    }
    atomicAdd(&ctx[b * HH + 2 * t], a0);
    atomicAdd(&ctx[b * HH + 2 * t + 1], a1);
}

// ---------------------------------------------------------------------------
// k_gates: gpart[ksl] = lstm_in @ W_ih^T + h @ W_hh^T  (K-slice partials).
// lstm_in = [emb16 bf16 | ctx f32 (cvt on the fly)]; h from h16v.
// grid 64 = 16 n-tiles(128) x 4 k-slices(384).
// ---------------------------------------------------------------------------
__global__ __launch_bounds__(256)
void k_gates(const unsigned short* __restrict__ emb16, const float* __restrict__ ctx,
             const unsigned short* __restrict__ h16v,
             const float* __restrict__ Wih, const float* __restrict__ Whh,
             float* __restrict__ gpart) {
    int nt = blockIdx.x >> 2, ksl = blockIdx.x & 3;
    int wave = threadIdx.x >> 6, lane = threadIdx.x & 63;
    int l15 = lane & 15, lq = lane >> 4, k0 = lq * 8;
    int n0w = nt * 128 + wave * 32;
    f32x4 acc[4][2];
#pragma unroll
    for (int mf = 0; mf < 4; ++mf)
#pragma unroll
        for (int nf = 0; nf < 2; ++nf) acc[mf][nf] = (f32x4){0.f, 0.f, 0.f, 0.f};

    for (int ks = 0; ks < 12; ++ks) {
        int kg = ksl * 384 + ks * 32;
        us8_t af[4];
        if (kg < 512) {
#pragma unroll
            for (int mf = 0; mf < 4; ++mf)
                af[mf] = *(const us8_t*)(emb16 + (mf * 16 + l15) * 512 + kg + k0);
        } else if (kg < 1024) {
#pragma unroll
            for (int mf = 0; mf < 4; ++mf) {
                const float* cr = ctx + (size_t)(mf * 16 + l15) * 512 + (kg - 512) + k0;
                af[mf] = pack8c(*(const float4*)cr, *(const float4*)(cr + 4));
            }
        } else {
#pragma unroll
            for (int mf = 0; mf < 4; ++mf)
                af[mf] = *(const us8_t*)(h16v + (mf * 16 + l15) * 512 + (kg - 1024) + k0);
        }
#pragma unroll
        for (int nf = 0; nf < 2; ++nf) {
            int n = n0w + nf * 16 + l15;
            us8_t bu;
            if (kg < 1024) {
                const float* wr = Wih + (size_t)n * 1024 + kg + k0;
                bu = pack8c(*(const float4*)wr, *(const float4*)(wr + 4));
            } else {
                const float* wr = Whh + (size_t)n * 512 + (kg - 1024) + k0;
                bu = pack8c(*(const float4*)wr, *(const float4*)(wr + 4));
            }
#pragma unroll
            for (int mf = 0; mf < 4; ++mf)
                acc[mf][nf] = __builtin_amdgcn_mfma_f32_16x16x32_bf16(
                    __builtin_bit_cast(bf16x8, af[mf]),
                    __builtin_bit_cast(bf16x8, bu), acc[mf][nf], 0, 0, 0);
        }
    }
#pragma unroll
    for (int mf = 0; mf < 4; ++mf)
#pragma unroll
        for (int nf = 0; nf < 2; ++nf)
#pragma unroll
            for (int r = 0; r < 4; ++r) {
                int row = mf * 16 + lq * 4 + r;
                int n = n0w + nf * 16 + l15;
                gpart[ksl * (BB * 2048) + row * 2048 + n] = acc[mf][nf][r];
            }
}

// ---------------------------------------------------------------------------
// k_lstm: sum K-slice partials + biases, pointwise cell update
// ---------------------------------------------------------------------------
__global__ __launch_bounds__(512)
void k_lstm(const float* __restrict__ gpart, const float* __restrict__ bih,
            const float* __restrict__ bhh, const float* __restrict__ cell,
            float* __restrict__ oh, float* __restrict__ oc,
            unsigned short* __restrict__ h116) {
    int b = blockIdx.x, t = threadIdx.x;
    float gi = bih[t] + bhh[t];
    float gf = bih[512 + t] + bhh[512 + t];
    float gg = bih[1024 + t] + bhh[1024 + t];
    float go = bih[1536 + t] + bhh[1536 + t];
#pragma unroll
    for (int ksl = 0; ksl < 4; ++ksl) {
        const float* gp = gpart + ksl * (BB * 2048) + b * 2048;
        gi += gp[t];
        gf += gp[512 + t];
        gg += gp[1024 + t];
        go += gp[1536 + t];
    }
    float c0 = cell[b * HH + t];
    float c1 = sigmf(gf) * c0 + sigmf(gi) * fast_tanh(gg);
    float h1 = sigmf(go) * fast_tanh(c1);
    oh[b * HH + t] = h1;
    oc[b * HH + t] = c1;
    h116[b * HH + t] = (unsigned short)(cvtpk(h1, h1) & 0xffffu);
}

// ---------------------------------------------------------------------------
// k_pred: pred = h1 @ W_out^T + b_out  (M=64, N=32000, K=512)
// ---------------------------------------------------------------------------
__global__ __launch_bounds__(512)
void k_pred(const unsigned short* __restrict__ h116, const float* __restrict__ Wout,
            const float* __restrict__ bout, float* __restrict__ pred) {
    int wave = threadIdx.x >> 6, lane = threadIdx.x & 63;
    int l15 = lane & 15, lq = lane >> 4, k0 = lq * 8;
    int n = blockIdx.x * 128 + wave * 16 + l15;
    f32x4 acc[4];
#pragma unroll
    for (int mf = 0; mf < 4; ++mf) acc[mf] = (f32x4){0.f, 0.f, 0.f, 0.f};
    const float* wr = Wout + (size_t)n * HH;
#pragma unroll 4
    for (int ks = 0; ks < 16; ++ks) {
        float4 x = *(const float4*)(wr + ks * 32 + k0);
        float4 y = *(const float4*)(wr + ks * 32 + k0 + 4);
        us8_t bu = pack8c(x, y);
#pragma unroll
        for (int mf = 0; mf < 4; ++mf) {
            us8_t au = *(const us8_t*)(h116 + (mf * 16 + l15) * 512 + ks * 32 + k0);
            acc[mf] = __builtin_amdgcn_mfma_f32_16x16x32_bf16(
                __builtin_bit_cast(bf16x8, au),
                __builtin_bit_cast(bf16x8, bu), acc[mf], 0, 0, 0);
        }
    }
    float bo = bout[n];
#pragma unroll
    for (int mf = 0; mf < 4; ++mf)
#pragma unroll
        for (int r = 0; r < 4; ++r) {
            int row = mf * 16 + lq * 4 + r;
            pred[(size_t)row * VV + n] = acc[mf][r] + bo;
        }
}

// ---------------------------------------------------------------------------
extern "C" void kernel_launch(void* const* d_in, const int* in_sizes, int n_in,
                              void* d_out, int out_size, void* d_ws, size_t ws_size,
                              hipStream_t stream) {
    const int* tok = (const int*)d_in[0];
    const float* hidden = (const float*)d_in[1];
    const float* cell = (const float*)d_in[2];
    const float* enc = (const float*)d_in[3];
    const float* pos = (const float*)d_in[4];
    const unsigned char* mask = (const unsigned char*)d_in[5];
    const float* embt = (const float*)d_in[6];
    const float* Ws = (const float*)d_in[7];
    const float* Wh = (const float*)d_in[8];
    const float* Vw = (const float*)d_in[9];
    const float* Wp = (const float*)d_in[10];
    const float* bp = (const float*)d_in[11];
    const float* Wih = (const float*)d_in[12];
    const float* Whh = (const float*)d_in[13];
    const float* bih = (const float*)d_in[14];
    const float* bhh = (const float*)d_in[15];
    const float* Wout = (const float*)d_in[16];
    const float* bout = (const float*)d_in[17];

    float* out = (float*)d_out;
    float* pred = out;                  // 64*32000
    float* out_h = out + 2048000;       // 64*512
    float* out_c = out + 2080768;       // 64*512
    float* attn = out + 2113536;        // 64*1024

    char* wsb = (char*)d_ws;
    unsigned short* wh16 = (unsigned short*)(wsb);                 // 512KB @0
    float* qs = (float*)(wsb + (512 << 10));                       // 128KB
    float* gate = (float*)(wsb + (640 << 10));                     // 256KB
    float* part = (float*)(wsb + (896 << 10));                     // 512KB (2 slabs)
    float* ctx = (float*)(wsb + (1408 << 10));                     // 128KB
    unsigned short* emb16 = (unsigned short*)(wsb + (1536 << 10)); // 64KB
    unsigned short* h16v = (unsigned short*)(wsb + (1600 << 10));  // 64KB
    float* gpart = (float*)(wsb + (1664 << 10));                   // 2MB
    unsigned short* h116 = (unsigned short*)(wsb + (3712 << 10));  // 64KB

    hipLaunchKernelGGL(k_pre, dim3(360), dim3(256), 0, stream,
                       hidden, Ws, Wh, pos, Wp, bp, tok, embt,
                       wh16, qs, gate, ctx, emb16, h16v);
    hipLaunchKernelGGL(k_scores, dim3(1024), dim3(512), 0, stream,
                       enc, wh16, qs, Vw, part);
    hipLaunchKernelGGL(k_context, dim3(1024), dim3(256), 0, stream,
                       enc, part, gate, mask, attn, ctx);
    hipLaunchKernelGGL(k_gates, dim3(64), dim3(256), 0, stream,
                       emb16, ctx, h16v, Wih, Whh, gpart);
    hipLaunchKernelGGL(k_lstm, dim3(64), dim3(512), 0, stream,
                       gpart, bih, bhh, cell, out_h, out_c, h116);
    hipLaunchKernelGGL(k_pred, dim3(250), dim3(512), 0, stream, h116, Wout, bout, pred);
}